// Round 11
// baseline (328.866 us; speedup 1.0000x reference)
//
#include <hip/hip_runtime.h>
#include <stdint.h>

#define B_ 2
#define S_ 2048
#define D_ 1024
#define H_ 16
#define HD_ 64
#define NT_ (S_ / 64)
// SCALE * log2(e): softmax computed in exp2 domain
#define SC2_ 0.18033688011112042f

typedef __bf16 bf16_t;
typedef bf16_t bf16x8 __attribute__((ext_vector_type(8)));
typedef float f32x4 __attribute__((ext_vector_type(4)));
typedef unsigned short u16x8 __attribute__((ext_vector_type(8)));
typedef unsigned short u16x4 __attribute__((ext_vector_type(4)));

static __device__ __forceinline__ unsigned short f2b(float f) {
  return __builtin_bit_cast(unsigned short, (bf16_t)f);   // native cvt (RNE)
}

static __device__ __forceinline__ bf16x8 asb(u16x8 u) {
  return __builtin_bit_cast(bf16x8, u);
}

// ---------------- cast fp32 -> bf16, fused launches ----------------
__global__ void cast3(const float* __restrict__ a, const float* __restrict__ b,
                      const float* __restrict__ c,
                      unsigned short* __restrict__ dst, int n) {
  const float* src = blockIdx.y == 0 ? a : (blockIdx.y == 1 ? b : c);
  unsigned short* d = dst + (size_t)blockIdx.y * n;
  int i = (blockIdx.x * blockDim.x + threadIdx.x) * 8;
  if (i >= n) return;
  float4 f0 = *(const float4*)(src + i);
  float4 f1 = *(const float4*)(src + i + 4);
  u16x8 o;
  o[0] = f2b(f0.x); o[1] = f2b(f0.y); o[2] = f2b(f0.z); o[3] = f2b(f0.w);
  o[4] = f2b(f1.x); o[5] = f2b(f1.y); o[6] = f2b(f1.z); o[7] = f2b(f1.w);
  *(u16x8*)(d + i) = o;
}

__global__ void cast4(const float* __restrict__ a, const float* __restrict__ b,
                      const float* __restrict__ c, const float* __restrict__ e,
                      unsigned short* __restrict__ dst, int n) {
  const float* src = blockIdx.y == 0 ? a
                   : (blockIdx.y == 1 ? b : (blockIdx.y == 2 ? c : e));
  unsigned short* d = dst + (size_t)blockIdx.y * n;
  int i = (blockIdx.x * blockDim.x + threadIdx.x) * 8;
  if (i >= n) return;
  float4 f0 = *(const float4*)(src + i);
  float4 f1 = *(const float4*)(src + i + 4);
  u16x8 o;
  o[0] = f2b(f0.x); o[1] = f2b(f0.y); o[2] = f2b(f0.z); o[3] = f2b(f0.w);
  o[4] = f2b(f1.x); o[5] = f2b(f1.y); o[6] = f2b(f1.z); o[7] = f2b(f1.w);
  *(u16x8*)(d + i) = o;
}

// ---------------- pack mask to bits via ballot ----------------
__global__ void pack_mask(const int* __restrict__ mask,
                          uint32_t* __restrict__ mbits) {
  int i = blockIdx.x * blockDim.x + threadIdx.x;
  unsigned long long bits = __ballot(mask[i] != 0);
  if ((threadIdx.x & 63) == 0)
    *(unsigned long long*)&mbits[i >> 5] = bits;
}

// ---------------- bf16 GEMM (r2 structure): C = A[M,K] @ W[N,K]^T + bias ----
// OUTMODE 0: z=0,1 -> bf16 head-split [B,H,S,HD]; z=2 -> bf16 V^T [B,H,HD,S].
// OUTMODE 1: fp32 row-major [M,N] (non-temporal: never re-read).
template<int OUTMODE>
__global__ __launch_bounds__(256)
void gemm_bt(const unsigned short* __restrict__ Ab,
             const unsigned short* __restrict__ Wb,
             const float* __restrict__ bq_,
             const float* __restrict__ bk_,
             const float* __restrict__ bv_,
             void* __restrict__ outv,
             int M, int N, int K) {
  const int z = blockIdx.z;
  const unsigned short* A = Ab + (size_t)z * M * K;
  const unsigned short* W = Wb + (size_t)z * N * K;
  const float* bias = z == 0 ? bq_ : (z == 1 ? bk_ : bv_);

  // padded stride 40 u16 = 80B (5 mod 8 -> 2-way bank spread on b128 reads)
  __shared__ __align__(16) unsigned short As[128 * 40];
  __shared__ __align__(16) unsigned short Bs[128 * 40];

  const int tid = threadIdx.x;
  const int lane = tid & 63;
  const int wave = tid >> 6;
  const int wm = wave >> 1, wn = wave & 1;
  const int row0 = blockIdx.x * 128;
  const int col0 = blockIdx.y * 128;

  const int srow = tid >> 2;        // 0..63
  const int scol = (tid & 3) * 8;   // 0,8,16,24
  const int lr = lane & 15;
  const int lg = lane >> 4;
  const int lk = lg * 8;

  f32x4 acc[4][4] = {};

  u16x8 a0 = *(const u16x8*)&A[(size_t)(row0 + srow) * K + scol];
  u16x8 a1 = *(const u16x8*)&A[(size_t)(row0 + srow + 64) * K + scol];
  u16x8 b0 = *(const u16x8*)&W[(size_t)(col0 + srow) * K + scol];
  u16x8 b1 = *(const u16x8*)&W[(size_t)(col0 + srow + 64) * K + scol];

  for (int k0 = 0; k0 < K; k0 += 32) {
    __syncthreads();   // prior iteration's LDS reads complete
    *(u16x8*)&As[srow * 40 + scol] = a0;
    *(u16x8*)&As[(srow + 64) * 40 + scol] = a1;
    *(u16x8*)&Bs[srow * 40 + scol] = b0;
    *(u16x8*)&Bs[(srow + 64) * 40 + scol] = b1;
    if (k0 + 32 < K) {
      a0 = *(const u16x8*)&A[(size_t)(row0 + srow) * K + k0 + 32 + scol];
      a1 = *(const u16x8*)&A[(size_t)(row0 + srow + 64) * K + k0 + 32 + scol];
      b0 = *(const u16x8*)&W[(size_t)(col0 + srow) * K + k0 + 32 + scol];
      b1 = *(const u16x8*)&W[(size_t)(col0 + srow + 64) * K + k0 + 32 + scol];
    }
    __syncthreads();

    bf16x8 af[4], bfr[4];
#pragma unroll
    for (int i = 0; i < 4; ++i)
      af[i] = asb(*(const u16x8*)&As[(wm * 64 + i * 16 + lr) * 40 + lk]);
#pragma unroll
    for (int j = 0; j < 4; ++j)
      bfr[j] = asb(*(const u16x8*)&Bs[(wn * 64 + j * 16 + lr) * 40 + lk]);
#pragma unroll
    for (int i = 0; i < 4; ++i)
#pragma unroll
      for (int j = 0; j < 4; ++j)
        acc[i][j] = __builtin_amdgcn_mfma_f32_16x16x32_bf16(af[i], bfr[j], acc[i][j], 0, 0, 0);
  }

  const size_t zo = (size_t)z * M * N;
#pragma unroll
  for (int i = 0; i < 4; ++i) {
#pragma unroll
    for (int j = 0; j < 4; ++j) {
      const int row_ = row0 + wm * 64 + i * 16 + lg * 4;
      const int col = col0 + wn * 64 + j * 16 + lr;
      const float bcol = bias[col];
      if (OUTMODE == 1) {
        float* O = (float*)outv;
#pragma unroll
        for (int r = 0; r < 4; ++r)
          __builtin_nontemporal_store(acc[i][j][r] + bcol,
                                      &O[(size_t)(row_ + r) * N + col]);
      } else if (z == 2) {
        // V^T: [bh][hd][s], 4 consecutive s per lane -> 8B store
        unsigned short* O = (unsigned short*)outv + zo;
        int b = row_ >> 11, s = row_ & 2047;
        int h = col >> 6, hd = col & 63;
        u16x4 pk;
#pragma unroll
        for (int r = 0; r < 4; ++r) pk[r] = f2b(acc[i][j][r] + bcol);
        *(u16x4*)&O[(((size_t)b * H_ + h) * HD_ + hd) * S_ + s] = pk;
      } else {
        unsigned short* O = (unsigned short*)outv + zo;
        int h = col >> 6, hd = col & 63;
#pragma unroll
        for (int r = 0; r < 4; ++r) {
          int row = row_ + r;
          int b = row >> 11, s = row & 2047;
          O[(((size_t)b * H_ + h) * S_ + s) * HD_ + hd] = f2b(acc[i][j][r] + bcol);
        }
      }
    }
  }
}

// XCD-aware remap for grid (32,32): each XCD owns 4 consecutive bh values so
// its private L2 keeps those heads' K/V/Q resident across all q-tiles.
static __device__ __forceinline__ void xcd_map(int& bh, int& qt) {
  int lin = blockIdx.y * 32 + blockIdx.x;
  int xcd = lin & 7, k = lin >> 3;          // 128 blocks per XCD
  bh = (xcd << 2) | (k >> 5);               // 4 heads per XCD
  qt = k & 31;
}

// ---------------- attention pass 1: per-row (m2, l), exp2 domain ------------
// 64 q-rows per block, 8 waves = 4 q-subtiles x 2 sk-halves; end-merge (m,l).
// Swapped QK^T: sa = mfma(K, Q) -> D col = sq, row = sk. Lane owns ONE sq row.
__global__ __launch_bounds__(512)
void attn_pass1(const unsigned short* __restrict__ q_bh,
                const unsigned short* __restrict__ k_bh,
                const uint32_t* __restrict__ mbits,
                float2* __restrict__ ml) {
  int bh, qt;
  xcd_map(bh, qt);
  const int b = bh >> 4;
  const int q0 = qt * 64;

  __shared__ __align__(16) unsigned short Ks[64 * 72];

  const int tid = threadIdx.x, lane = tid & 63, w = tid >> 6;   // w 0..7
  const int wq = w >> 1, wk = w & 1;
  const int srow = tid >> 3, scol = (tid & 7) * 8;              // srow 0..63
  const int lr = lane & 15, lg = lane >> 4, lk = lg * 8;
  const int sq = q0 + wq * 16 + lr;

  const unsigned short* qb = q_bh + ((size_t)bh * S_ + sq) * HD_;
  bf16x8 qf0 = asb(*(const u16x8*)&qb[lk]);
  bf16x8 qf1 = asb(*(const u16x8*)&qb[32 + lk]);

  const uint32_t* mrow = mbits + ((size_t)b * S_ + sq) * (S_ / 32);
  const unsigned short* kb = k_bh + (size_t)bh * S_ * HD_;

  float m2 = -__builtin_inff(), l = 0.f;

  u16x8 t0 = *(const u16x8*)&kb[srow * 64 + scol];

  for (int kt = 0; kt < NT_; ++kt) {
    __syncthreads();
    *(u16x8*)&Ks[srow * 72 + scol] = t0;
    if (kt + 1 < NT_) {
      const unsigned short* kn = kb + (kt + 1) * 64 * 64;
      t0 = *(const u16x8*)&kn[srow * 64 + scol];
    }
    __syncthreads();

    uint32_t mw = mrow[kt * 2 + wk];
    const bool full = __all(mw == 0xffffffffu);

    f32x4 sa[2] = {};
#pragma unroll
    for (int jj = 0; jj < 2; ++jj) {
      const int j = wk * 2 + jj;
      bf16x8 kf0 = asb(*(const u16x8*)&Ks[(j * 16 + lr) * 72 + lk]);
      bf16x8 kf1 = asb(*(const u16x8*)&Ks[(j * 16 + lr) * 72 + 32 + lk]);
      sa[jj] = __builtin_amdgcn_mfma_f32_16x16x32_bf16(kf0, qf0, sa[jj], 0, 0, 0);
      sa[jj] = __builtin_amdgcn_mfma_f32_16x16x32_bf16(kf1, qf1, sa[jj], 0, 0, 0);
    }

    float sv[2][4];
    if (full) {
#pragma unroll
      for (int jj = 0; jj < 2; ++jj)
#pragma unroll
        for (int r = 0; r < 4; ++r) sv[jj][r] = sa[jj][r] * SC2_;
    } else {
#pragma unroll
      for (int jj = 0; jj < 2; ++jj)
#pragma unroll
        for (int r = 0; r < 4; ++r) {
          int bit = jj * 16 + lg * 4 + r;
          sv[jj][r] = ((mw >> bit) & 1) ? sa[jj][r] * SC2_ : -3.0e9f;
        }
    }
    float tm = sv[0][0];
#pragma unroll
    for (int jj = 0; jj < 2; ++jj)
#pragma unroll
      for (int r = 0; r < 4; ++r) tm = fmaxf(tm, sv[jj][r]);
    tm = fmaxf(tm, __shfl_xor(tm, 16));
    tm = fmaxf(tm, __shfl_xor(tm, 32));
    float mnew = fmaxf(m2, tm);
    float ss = 0.f;
#pragma unroll
    for (int jj = 0; jj < 2; ++jj)
#pragma unroll
      for (int r = 0; r < 4; ++r)
        ss += __builtin_amdgcn_exp2f(sv[jj][r] - mnew);
    ss += __shfl_xor(ss, 16);
    ss += __shfl_xor(ss, 32);
    l = l * __builtin_amdgcn_exp2f(m2 - mnew) + ss;
    m2 = mnew;
  }

  // merge the two sk-halves (wk=0,1) of each q row
  __syncthreads();                       // Ks reads done; safe to overlay
  float2* mls = (float2*)Ks;             // 64 float2 = 512B
  if (wk == 1 && lg == 0) mls[wq * 16 + lr] = make_float2(m2, l);
  __syncthreads();
  if (wk == 0 && lg == 0) {
    float2 o = mls[wq * 16 + lr];
    float mn = fmaxf(m2, o.x);
    float lo = l * __builtin_amdgcn_exp2f(m2 - mn) +
               o.y * __builtin_amdgcn_exp2f(o.x - mn);
    ml[(size_t)bh * S_ + sq] = make_float2(mn, lo);
  }
}

// ---------------- attention pass 2: normalized weights + PV ----------------
// 8 waves = 4 q-subtiles x 2 sk-halves; partial PV combined at end via LDS.
// V^T fragments read DIRECTLY from global (L2-resident via XCD swizzle) --
// issued early (between barriers), consumed after QK+softmax.
__global__ __launch_bounds__(512)
void attn_pass2(const unsigned short* __restrict__ q_bh,
                const unsigned short* __restrict__ k_bh,
                const unsigned short* __restrict__ vt_g,
                const uint32_t* __restrict__ mbits,
                const float2* __restrict__ ml,
                float* __restrict__ w_out,
                unsigned short* __restrict__ attn_out) {
  int bh, qt;
  xcd_map(bh, qt);
  const int b = bh >> 4, h = bh & (H_ - 1);
  const int q0 = qt * 64;

  __shared__ __align__(16) unsigned char smem[27648];
  unsigned short* Ks = (unsigned short*)smem;        // [64*72]  9216B
  unsigned short* Ps = Ks + 64 * 72;                 // [8][16*72] 18432B
  float* cs = (float*)smem;                          // end-overlay, 17408B

  const int tid = threadIdx.x, lane = tid & 63, w = tid >> 6;
  const int wq = w >> 1, wk = w & 1;
  const int srow = tid >> 3, scol = (tid & 7) * 8;   // srow 0..63
  const int lr = lane & 15, lg = lane >> 4, lk = lg * 8;
  const int sq = q0 + wq * 16 + lr;
  unsigned short* Psw = Ps + w * (16 * 72);

  const unsigned short* qb = q_bh + ((size_t)bh * S_ + sq) * HD_;
  bf16x8 qf0 = asb(*(const u16x8*)&qb[lk]);
  bf16x8 qf1 = asb(*(const u16x8*)&qb[32 + lk]);

  // p = exp2(sa*SC2 + off), off = -m2 - log2(l)  (normalization folded in)
  float2 t = ml[(size_t)bh * S_ + sq];
  const float off = -t.x - __builtin_amdgcn_logf(t.y);
  const uint32_t* mrow = mbits + ((size_t)b * S_ + sq) * (S_ / 32);
  float* wrow = w_out + ((size_t)bh * S_ + sq) * S_;

  const unsigned short* kb = k_bh + (size_t)bh * S_ * HD_;
  const unsigned short* vb = vt_g + (size_t)bh * HD_ * S_;

  u16x8 t0 = *(const u16x8*)&kb[srow * 64 + scol];

  f32x4 oacc[4] = {};

  for (int kt = 0; kt < NT_; ++kt) {
    const int k0 = kt * 64;
    __syncthreads();   // prior iteration's QK/Ps LDS reads complete
    *(u16x8*)&Ks[srow * 72 + scol] = t0;
    if (kt + 1 < NT_) {
      t0 = *(const u16x8*)&kb[(k0 + 64 + srow) * 64 + scol];
    }
    // early V-frag loads: global (L2-hit), independent of barriers; latency
    // hides under QK + softmax below
    u16x8 vfr[4];
#pragma unroll
    for (int j2 = 0; j2 < 4; ++j2)
      vfr[j2] = *(const u16x8*)&vb[(size_t)(j2 * 16 + lr) * S_ + k0 + wk * 32 + lk];
    __syncthreads();

    uint32_t mw = mrow[kt * 2 + wk];
    const bool full = __all(mw == 0xffffffffu);

    f32x4 sa[2] = {};
#pragma unroll
    for (int jj = 0; jj < 2; ++jj) {
      const int j = wk * 2 + jj;
      bf16x8 kf0 = asb(*(const u16x8*)&Ks[(j * 16 + lr) * 72 + lk]);
      bf16x8 kf1 = asb(*(const u16x8*)&Ks[(j * 16 + lr) * 72 + 32 + lk]);
      sa[jj] = __builtin_amdgcn_mfma_f32_16x16x32_bf16(kf0, qf0, sa[jj], 0, 0, 0);
      sa[jj] = __builtin_amdgcn_mfma_f32_16x16x32_bf16(kf1, qf1, sa[jj], 0, 0, 0);
    }

    // weights: lane owns row sq; sk = k0 + wk*32 + jj*16 + lg*4 + r
#pragma unroll
    for (int jj = 0; jj < 2; ++jj) {
      f32x4 pv;
      u16x4 pb;
      if (full) {
#pragma unroll
        for (int r = 0; r < 4; ++r) {
          float p = __builtin_amdgcn_exp2f(fmaf(sa[jj][r], SC2_, off));
          pv[r] = p;
          pb[r] = f2b(p);
        }
      } else {
#pragma unroll
        for (int r = 0; r < 4; ++r) {
          int bit = jj * 16 + lg * 4 + r;
          float x = ((mw >> bit) & 1) ? fmaf(sa[jj][r], SC2_, off) : -3.0e9f;
          float p = __builtin_amdgcn_exp2f(x);
          pv[r] = p;
          pb[r] = f2b(p);
        }
      }
      // streaming store: bypass L2 so K/V stay resident
      __builtin_nontemporal_store(pv,
          (f32x4*)&wrow[k0 + wk * 32 + jj * 16 + lg * 4]);
      *(u16x4*)&Psw[lr * 72 + wk * 32 + jj * 16 + lg * 4] = pb;
    }

    // PV over this wave's 32-sk slice: A = P (row=sq), B = V^T frags (col=hd)
    bf16x8 pa = asb(*(const u16x8*)&Psw[lr * 72 + wk * 32 + lk]);
#pragma unroll
    for (int j2 = 0; j2 < 4; ++j2) {
      oacc[j2] = __builtin_amdgcn_mfma_f32_16x16x32_bf16(pa, asb(vfr[j2]), oacc[j2], 0, 0, 0);
    }
  }

  // combine sk-half partials: wave (wq,1) -> LDS, wave (wq,0) adds + stores
  __syncthreads();                      // all tile LDS reads done; overlay safe
  const int ci = (wq * 64 + lane) * 17; // 17-dword stride: conflict-free
  if (wk == 1) {
#pragma unroll
    for (int j2 = 0; j2 < 4; ++j2)
#pragma unroll
      for (int r = 0; r < 4; ++r) cs[ci + j2 * 4 + r] = oacc[j2][r];
  }
  __syncthreads();
  if (wk == 0) {
    // D: col = hd = j2*16+lr, row = sq-local = lg*4+r
#pragma unroll
    for (int j2 = 0; j2 < 4; ++j2)
#pragma unroll
      for (int r = 0; r < 4; ++r) {
        float v = oacc[j2][r] + cs[ci + j2 * 4 + r];
        attn_out[((size_t)b * S_ + q0 + wq * 16 + lg * 4 + r) * D_ + h * HD_ + j2 * 16 + lr] =
            f2b(v);
      }
  }
}

// ---------------- launch ----------------
extern "C" void kernel_launch(void* const* d_in, const int* in_sizes, int n_in,
                              void* d_out, int out_size, void* d_ws, size_t ws_size,
                              hipStream_t stream) {
  const float* query = (const float*)d_in[0];
  const float* key   = (const float*)d_in[1];
  const float* value = (const float*)d_in[2];
  const int*   mask  = (const int*)d_in[3];
  const float* Wq = (const float*)d_in[4];
  const float* bq = (const float*)d_in[5];
  const float* Wk = (const float*)d_in[6];
  const float* bk = (const float*)d_in[7];
  const float* Wv = (const float*)d_in[8];
  const float* bv = (const float*)d_in[9];
  const float* Wo = (const float*)d_in[10];
  const float* bo = (const float*)d_in[11];

  const int NE = B_ * S_ * D_;   // 4194304
  const int NW = D_ * D_;        // 1048576

  char* ws = (char*)d_ws;
  unsigned short* xin  = (unsigned short*)(ws);              // 3*NE bf16, dead after proj
  uint32_t*       mbits = (uint32_t*)(ws + 8388608);         // 1MB, inside dead xin
  unsigned short* wbuf = (unsigned short*)(ws + 25165824);   // 4*NW bf16
  unsigned short* qkv  = (unsigned short*)(ws + 33554432);   // 3*NE bf16 (v stored ^T)
  float2* mlbuf        = (float2*)(ws + 58720256);           // 524288
  unsigned short* aout = (unsigned short*)(ws + 59244544);   // NE bf16

  cast3<<<dim3(NE / 2048, 3), dim3(256), 0, stream>>>(query, key, value, xin, NE);
  cast4<<<dim3(NW / 2048, 4), dim3(256), 0, stream>>>(Wq, Wk, Wv, Wo, wbuf, NW);

  // q,k,v projections (z = 0,1,2); z==2 writes V transposed per head
  gemm_bt<0><<<dim3(32, 8, 3), dim3(256), 0, stream>>>(
      xin, wbuf, bq, bk, bv, qkv, 4096, 1024, 1024);

  // xin dead now: build mask bits there
  pack_mask<<<dim3(B_ * S_ * S_ / 256), dim3(256), 0, stream>>>(mask, mbits);

  float* w_out = (float*)d_out + NE;   // attn_weights region
  attn_pass1<<<dim3(32, 32), dim3(512), 0, stream>>>(qkv, qkv + NE, mbits, mlbuf);
  attn_pass2<<<dim3(32, 32), dim3(512), 0, stream>>>(
      qkv, qkv + NE, qkv + 2 * NE, mbits, mlbuf, w_out, aout);

  // output projection -> fp32 d_out
  gemm_bt<1><<<dim3(32, 8, 1), dim3(256), 0, stream>>>(
      aout, wbuf + 3 * NW, bo, bo, bo, d_out, 4096, 1024, 1024);
}

// Round 12
// 305.585 us; speedup vs baseline: 1.0762x; 1.0762x over previous
//
#include <hip/hip_runtime.h>
#include <stdint.h>

#define B_ 2
#define S_ 2048
#define D_ 1024
#define H_ 16
#define HD_ 64
#define NT_ (S_ / 64)
// SCALE * log2(e): softmax computed in exp2 domain
#define SC2_ 0.18033688011112042f

typedef __bf16 bf16_t;
typedef bf16_t bf16x8 __attribute__((ext_vector_type(8)));
typedef float f32x4 __attribute__((ext_vector_type(4)));
typedef unsigned short u16x8 __attribute__((ext_vector_type(8)));
typedef unsigned short u16x4 __attribute__((ext_vector_type(4)));

static __device__ __forceinline__ unsigned short f2b(float f) {
  return __builtin_bit_cast(unsigned short, (bf16_t)f);   // native cvt (RNE)
}

static __device__ __forceinline__ bf16x8 asb(u16x8 u) {
  return __builtin_bit_cast(bf16x8, u);
}

static __device__ __forceinline__ void gload16(const unsigned short* g,
                                               unsigned short* l) {
  __builtin_amdgcn_global_load_lds(
      (const __attribute__((address_space(1))) void*)g,
      (__attribute__((address_space(3))) void*)l, 16, 0, 0);
}

// ---------------- cast fp32 -> bf16, fused launches ----------------
__global__ void cast3(const float* __restrict__ a, const float* __restrict__ b,
                      const float* __restrict__ c,
                      unsigned short* __restrict__ dst, int n) {
  const float* src = blockIdx.y == 0 ? a : (blockIdx.y == 1 ? b : c);
  unsigned short* d = dst + (size_t)blockIdx.y * n;
  int i = (blockIdx.x * blockDim.x + threadIdx.x) * 8;
  if (i >= n) return;
  float4 f0 = *(const float4*)(src + i);
  float4 f1 = *(const float4*)(src + i + 4);
  u16x8 o;
  o[0] = f2b(f0.x); o[1] = f2b(f0.y); o[2] = f2b(f0.z); o[3] = f2b(f0.w);
  o[4] = f2b(f1.x); o[5] = f2b(f1.y); o[6] = f2b(f1.z); o[7] = f2b(f1.w);
  *(u16x8*)(d + i) = o;
}

__global__ void cast4(const float* __restrict__ a, const float* __restrict__ b,
                      const float* __restrict__ c, const float* __restrict__ e,
                      unsigned short* __restrict__ dst, int n) {
  const float* src = blockIdx.y == 0 ? a
                   : (blockIdx.y == 1 ? b : (blockIdx.y == 2 ? c : e));
  unsigned short* d = dst + (size_t)blockIdx.y * n;
  int i = (blockIdx.x * blockDim.x + threadIdx.x) * 8;
  if (i >= n) return;
  float4 f0 = *(const float4*)(src + i);
  float4 f1 = *(const float4*)(src + i + 4);
  u16x8 o;
  o[0] = f2b(f0.x); o[1] = f2b(f0.y); o[2] = f2b(f0.z); o[3] = f2b(f0.w);
  o[4] = f2b(f1.x); o[5] = f2b(f1.y); o[6] = f2b(f1.z); o[7] = f2b(f1.w);
  *(u16x8*)(d + i) = o;
}

// ---------------- pack mask to bits via ballot ----------------
__global__ void pack_mask(const int* __restrict__ mask,
                          uint32_t* __restrict__ mbits) {
  int i = blockIdx.x * blockDim.x + threadIdx.x;
  unsigned long long bits = __ballot(mask[i] != 0);
  if ((threadIdx.x & 63) == 0)
    *(unsigned long long*)&mbits[i >> 5] = bits;
}

// ---------------- bf16 GEMM (m97 structure): C = A[M,K] @ W[N,K]^T + bias ---
// global_load_lds width-16 staging into linear [128][32] LDS (m151: beats
// reg-staged at this tile). OUTMODE 0: z=0,1 -> bf16 head-split [B,H,S,HD];
// z=2 -> bf16 V^T [B,H,HD,S]. OUTMODE 1: fp32 row-major [M,N] (nt stores).
template<int OUTMODE>
__global__ __launch_bounds__(256)
void gemm_bt(const unsigned short* __restrict__ Ab,
             const unsigned short* __restrict__ Wb,
             const float* __restrict__ bq_,
             const float* __restrict__ bk_,
             const float* __restrict__ bv_,
             void* __restrict__ outv,
             int M, int N, int K) {
  const int z = blockIdx.z;
  const unsigned short* A = Ab + (size_t)z * M * K;
  const unsigned short* W = Wb + (size_t)z * N * K;
  const float* bias = z == 0 ? bq_ : (z == 1 ? bk_ : bv_);

  __shared__ __align__(16) unsigned short As[128 * 32];
  __shared__ __align__(16) unsigned short Bs[128 * 32];

  const int tid = threadIdx.x;
  const int lane = tid & 63;
  const int wave = tid >> 6;
  const int wm = wave >> 1, wn = wave & 1;
  const int row0 = blockIdx.x * 128;
  const int col0 = blockIdx.y * 128;

  const int lr = lane & 15;
  const int lg = lane >> 4;
  const int lk = lg * 8;

  // staging: wave-uniform LDS dest + lane*16B linear fill (global_load_lds)
  const int srow = wave * 16 + (lane >> 2);   // 16 rows per wave
  const int scol = (lane & 3) * 8;
  const unsigned short* a_src0 = &A[(size_t)(row0 + srow) * K + scol];
  const unsigned short* a_src1 = &A[(size_t)(row0 + 64 + srow) * K + scol];
  const unsigned short* b_src0 = &W[(size_t)(col0 + srow) * K + scol];
  const unsigned short* b_src1 = &W[(size_t)(col0 + 64 + srow) * K + scol];
  unsigned short* a_dst0 = &As[(wave * 16) * 32];
  unsigned short* a_dst1 = &As[(64 + wave * 16) * 32];
  unsigned short* b_dst0 = &Bs[(wave * 16) * 32];
  unsigned short* b_dst1 = &Bs[(64 + wave * 16) * 32];

  f32x4 acc[4][4] = {};

  for (int k0 = 0; k0 < K; k0 += 32) {
    __syncthreads();   // prior frag reads done
    gload16(a_src0 + k0, a_dst0);
    gload16(a_src1 + k0, a_dst1);
    gload16(b_src0 + k0, b_dst0);
    gload16(b_src1 + k0, b_dst1);
    __syncthreads();   // vmcnt drained -> LDS ready

    bf16x8 af[4], bfr[4];
#pragma unroll
    for (int i = 0; i < 4; ++i)
      af[i] = asb(*(const u16x8*)&As[(wm * 64 + i * 16 + lr) * 32 + lk]);
#pragma unroll
    for (int j = 0; j < 4; ++j)
      bfr[j] = asb(*(const u16x8*)&Bs[(wn * 64 + j * 16 + lr) * 32 + lk]);
#pragma unroll
    for (int i = 0; i < 4; ++i)
#pragma unroll
      for (int j = 0; j < 4; ++j)
        acc[i][j] = __builtin_amdgcn_mfma_f32_16x16x32_bf16(af[i], bfr[j], acc[i][j], 0, 0, 0);
  }

  const size_t zo = (size_t)z * M * N;
#pragma unroll
  for (int i = 0; i < 4; ++i) {
#pragma unroll
    for (int j = 0; j < 4; ++j) {
      const int row_ = row0 + wm * 64 + i * 16 + lg * 4;
      const int col = col0 + wn * 64 + j * 16 + lr;
      const float bcol = bias[col];
      if (OUTMODE == 1) {
        float* O = (float*)outv;
#pragma unroll
        for (int r = 0; r < 4; ++r)
          __builtin_nontemporal_store(acc[i][j][r] + bcol,
                                      &O[(size_t)(row_ + r) * N + col]);
      } else if (z == 2) {
        // V^T: [bh][hd][s], 4 consecutive s per lane -> 8B store
        unsigned short* O = (unsigned short*)outv + zo;
        int b = row_ >> 11, s = row_ & 2047;
        int h = col >> 6, hd = col & 63;
        u16x4 pk;
#pragma unroll
        for (int r = 0; r < 4; ++r) pk[r] = f2b(acc[i][j][r] + bcol);
        *(u16x4*)&O[(((size_t)b * H_ + h) * HD_ + hd) * S_ + s] = pk;
      } else {
        unsigned short* O = (unsigned short*)outv + zo;
        int h = col >> 6, hd = col & 63;
#pragma unroll
        for (int r = 0; r < 4; ++r) {
          int row = row_ + r;
          int b = row >> 11, s = row & 2047;
          O[(((size_t)b * H_ + h) * S_ + s) * HD_ + hd] = f2b(acc[i][j][r] + bcol);
        }
      }
    }
  }
}

// XCD-aware remap for grid (32,32): each XCD owns 4 consecutive bh values so
// its private L2 keeps those heads' K/V/Q resident across all q-tiles.
static __device__ __forceinline__ void xcd_map(int& bh, int& qt) {
  int lin = blockIdx.y * 32 + blockIdx.x;
  int xcd = lin & 7, k = lin >> 3;          // 128 blocks per XCD
  bh = (xcd << 2) | (k >> 5);               // 4 heads per XCD
  qt = k & 31;
}

// ---------------- attention pass 1: per-row (m2, l), exp2 domain ------------
// 64 q-rows per block, 8 waves = 4 q-subtiles x 2 sk-halves; end-merge (m,l).
// Swapped QK^T: sa = mfma(K, Q) -> D col = sq, row = sk. Lane owns ONE sq row.
__global__ __launch_bounds__(512)
void attn_pass1(const unsigned short* __restrict__ q_bh,
                const unsigned short* __restrict__ k_bh,
                const uint32_t* __restrict__ mbits,
                float2* __restrict__ ml) {
  int bh, qt;
  xcd_map(bh, qt);
  const int b = bh >> 4;
  const int q0 = qt * 64;

  __shared__ __align__(16) unsigned short Ks[64 * 72];

  const int tid = threadIdx.x, lane = tid & 63, w = tid >> 6;   // w 0..7
  const int wq = w >> 1, wk = w & 1;
  const int srow = tid >> 3, scol = (tid & 7) * 8;              // srow 0..63
  const int lr = lane & 15, lg = lane >> 4, lk = lg * 8;
  const int sq = q0 + wq * 16 + lr;

  const unsigned short* qb = q_bh + ((size_t)bh * S_ + sq) * HD_;
  bf16x8 qf0 = asb(*(const u16x8*)&qb[lk]);
  bf16x8 qf1 = asb(*(const u16x8*)&qb[32 + lk]);

  const uint32_t* mrow = mbits + ((size_t)b * S_ + sq) * (S_ / 32);
  const unsigned short* kb = k_bh + (size_t)bh * S_ * HD_;

  float m2 = -__builtin_inff(), l = 0.f;

  u16x8 t0 = *(const u16x8*)&kb[srow * 64 + scol];

  for (int kt = 0; kt < NT_; ++kt) {
    __syncthreads();
    *(u16x8*)&Ks[srow * 72 + scol] = t0;
    if (kt + 1 < NT_) {
      const unsigned short* kn = kb + (kt + 1) * 64 * 64;
      t0 = *(const u16x8*)&kn[srow * 64 + scol];
    }
    __syncthreads();

    uint32_t mw = mrow[kt * 2 + wk];
    const bool full = __all(mw == 0xffffffffu);

    f32x4 sa[2] = {};
#pragma unroll
    for (int jj = 0; jj < 2; ++jj) {
      const int j = wk * 2 + jj;
      bf16x8 kf0 = asb(*(const u16x8*)&Ks[(j * 16 + lr) * 72 + lk]);
      bf16x8 kf1 = asb(*(const u16x8*)&Ks[(j * 16 + lr) * 72 + 32 + lk]);
      sa[jj] = __builtin_amdgcn_mfma_f32_16x16x32_bf16(kf0, qf0, sa[jj], 0, 0, 0);
      sa[jj] = __builtin_amdgcn_mfma_f32_16x16x32_bf16(kf1, qf1, sa[jj], 0, 0, 0);
    }

    float sv[2][4];
    if (full) {
#pragma unroll
      for (int jj = 0; jj < 2; ++jj)
#pragma unroll
        for (int r = 0; r < 4; ++r) sv[jj][r] = sa[jj][r] * SC2_;
    } else {
#pragma unroll
      for (int jj = 0; jj < 2; ++jj)
#pragma unroll
        for (int r = 0; r < 4; ++r) {
          int bit = jj * 16 + lg * 4 + r;
          sv[jj][r] = ((mw >> bit) & 1) ? sa[jj][r] * SC2_ : -3.0e9f;
        }
    }
    float tm = sv[0][0];
#pragma unroll
    for (int jj = 0; jj < 2; ++jj)
#pragma unroll
      for (int r = 0; r < 4; ++r) tm = fmaxf(tm, sv[jj][r]);
    tm = fmaxf(tm, __shfl_xor(tm, 16));
    tm = fmaxf(tm, __shfl_xor(tm, 32));
    float mnew = fmaxf(m2, tm);
    float ss = 0.f;
#pragma unroll
    for (int jj = 0; jj < 2; ++jj)
#pragma unroll
      for (int r = 0; r < 4; ++r)
        ss += __builtin_amdgcn_exp2f(sv[jj][r] - mnew);
    ss += __shfl_xor(ss, 16);
    ss += __shfl_xor(ss, 32);
    l = l * __builtin_amdgcn_exp2f(m2 - mnew) + ss;
    m2 = mnew;
  }

  // merge the two sk-halves (wk=0,1) of each q row
  __syncthreads();                       // Ks reads done; safe to overlay
  float2* mls = (float2*)Ks;             // 64 float2 = 512B
  if (wk == 1 && lg == 0) mls[wq * 16 + lr] = make_float2(m2, l);
  __syncthreads();
  if (wk == 0 && lg == 0) {
    float2 o = mls[wq * 16 + lr];
    float mn = fmaxf(m2, o.x);
    float lo = l * __builtin_amdgcn_exp2f(m2 - mn) +
               o.y * __builtin_amdgcn_exp2f(o.x - mn);
    ml[(size_t)bh * S_ + sq] = make_float2(mn, lo);
  }
}

// ---------------- attention pass 2: normalized weights + PV ----------------
// 8 waves = 4 q-subtiles x 2 sk-halves; partial PV combined at end via LDS.
__global__ __launch_bounds__(512)
void attn_pass2(const unsigned short* __restrict__ q_bh,
                const unsigned short* __restrict__ k_bh,
                const unsigned short* __restrict__ vt_g,
                const uint32_t* __restrict__ mbits,
                const float2* __restrict__ ml,
                float* __restrict__ w_out,
                unsigned short* __restrict__ attn_out) {
  int bh, qt;
  xcd_map(bh, qt);
  const int b = bh >> 4, h = bh & (H_ - 1);
  const int q0 = qt * 64;

  __shared__ __align__(16) unsigned char smem[36864];
  unsigned short* Ks = (unsigned short*)smem;        // [64*72]  9216B
  unsigned short* Vs = Ks + 64 * 72;                 // [64*72]  9216B
  unsigned short* Ps = Vs + 64 * 72;                 // [8][16*72] 18432B
  float* cs = (float*)smem;                          // end-overlay, 17408B

  const int tid = threadIdx.x, lane = tid & 63, w = tid >> 6;
  const int wq = w >> 1, wk = w & 1;
  const int srow = tid >> 3, scol = (tid & 7) * 8;   // srow 0..63
  const int lr = lane & 15, lg = lane >> 4, lk = lg * 8;
  const int sq = q0 + wq * 16 + lr;
  unsigned short* Psw = Ps + w * (16 * 72);

  const unsigned short* qb = q_bh + ((size_t)bh * S_ + sq) * HD_;
  bf16x8 qf0 = asb(*(const u16x8*)&qb[lk]);
  bf16x8 qf1 = asb(*(const u16x8*)&qb[32 + lk]);

  // p = exp2(sa*SC2 + off), off = -m2 - log2(l)  (normalization folded in)
  float2 t = ml[(size_t)bh * S_ + sq];
  const float off = -t.x - __builtin_amdgcn_logf(t.y);
  const uint32_t* mrow = mbits + ((size_t)b * S_ + sq) * (S_ / 32);
  float* wrow = w_out + ((size_t)bh * S_ + sq) * S_;

  const unsigned short* kb = k_bh + (size_t)bh * S_ * HD_;
  const unsigned short* vb = vt_g + (size_t)bh * HD_ * S_;

  u16x8 t0 = *(const u16x8*)&kb[srow * 64 + scol];
  u16x8 v0 = *(const u16x8*)&vb[(size_t)srow * S_ + scol];

  f32x4 oacc[4] = {};

  for (int kt = 0; kt < NT_; ++kt) {
    const int k0 = kt * 64;
    __syncthreads();   // prior iteration's QK/PV LDS reads complete
    *(u16x8*)&Ks[srow * 72 + scol] = t0;
    *(u16x8*)&Vs[srow * 72 + scol] = v0;
    if (kt + 1 < NT_) {
      t0 = *(const u16x8*)&kb[(k0 + 64 + srow) * 64 + scol];
      v0 = *(const u16x8*)&vb[(size_t)srow * S_ + k0 + 64 + scol];
    }
    __syncthreads();

    uint32_t mw = mrow[kt * 2 + wk];
    const bool full = __all(mw == 0xffffffffu);

    f32x4 sa[2] = {};
#pragma unroll
    for (int jj = 0; jj < 2; ++jj) {
      const int j = wk * 2 + jj;
      bf16x8 kf0 = asb(*(const u16x8*)&Ks[(j * 16 + lr) * 72 + lk]);
      bf16x8 kf1 = asb(*(const u16x8*)&Ks[(j * 16 + lr) * 72 + 32 + lk]);
      sa[jj] = __builtin_amdgcn_mfma_f32_16x16x32_bf16(kf0, qf0, sa[jj], 0, 0, 0);
      sa[jj] = __builtin_amdgcn_mfma_f32_16x16x32_bf16(kf1, qf1, sa[jj], 0, 0, 0);
    }

    // weights: lane owns row sq; sk = k0 + wk*32 + jj*16 + lg*4 + r
#pragma unroll
    for (int jj = 0; jj < 2; ++jj) {
      f32x4 pv;
      u16x4 pb;
      if (full) {
#pragma unroll
        for (int r = 0; r < 4; ++r) {
          float p = __builtin_amdgcn_exp2f(fmaf(sa[jj][r], SC2_, off));
          pv[r] = p;
          pb[r] = f2b(p);
        }
      } else {
#pragma unroll
        for (int r = 0; r < 4; ++r) {
          int bit = jj * 16 + lg * 4 + r;
          float x = ((mw >> bit) & 1) ? fmaf(sa[jj][r], SC2_, off) : -3.0e9f;
          float p = __builtin_amdgcn_exp2f(x);
          pv[r] = p;
          pb[r] = f2b(p);
        }
      }
      // streaming store: bypass L2 so K/V stay resident
      __builtin_nontemporal_store(pv,
          (f32x4*)&wrow[k0 + wk * 32 + jj * 16 + lg * 4]);
      *(u16x4*)&Psw[lr * 72 + wk * 32 + jj * 16 + lg * 4] = pb;
    }

    // PV over this wave's 32-sk slice: A = P (row=sq), B = V^T (col=hd)
    bf16x8 pa = asb(*(const u16x8*)&Psw[lr * 72 + wk * 32 + lk]);
#pragma unroll
    for (int j2 = 0; j2 < 4; ++j2) {
      bf16x8 vf = asb(*(const u16x8*)&Vs[(j2 * 16 + lr) * 72 + wk * 32 + lk]);
      oacc[j2] = __builtin_amdgcn_mfma_f32_16x16x32_bf16(pa, vf, oacc[j2], 0, 0, 0);
    }
  }

  // combine sk-half partials: wave (wq,1) -> LDS, wave (wq,0) adds + stores
  __syncthreads();                      // all tile LDS reads done; overlay safe
  const int ci = (wq * 64 + lane) * 17; // 17-dword stride: conflict-free
  if (wk == 1) {
#pragma unroll
    for (int j2 = 0; j2 < 4; ++j2)
#pragma unroll
      for (int r = 0; r < 4; ++r) cs[ci + j2 * 4 + r] = oacc[j2][r];
  }
  __syncthreads();
  if (wk == 0) {
    // D: col = hd = j2*16+lr, row = sq-local = lg*4+r
#pragma unroll
    for (int j2 = 0; j2 < 4; ++j2)
#pragma unroll
      for (int r = 0; r < 4; ++r) {
        float v = oacc[j2][r] + cs[ci + j2 * 4 + r];
        attn_out[((size_t)b * S_ + q0 + wq * 16 + lg * 4 + r) * D_ + h * HD_ + j2 * 16 + lr] =
            f2b(v);
      }
  }
}

// ---------------- launch ----------------
extern "C" void kernel_launch(void* const* d_in, const int* in_sizes, int n_in,
                              void* d_out, int out_size, void* d_ws, size_t ws_size,
                              hipStream_t stream) {
  const float* query = (const float*)d_in[0];
  const float* key   = (const float*)d_in[1];
  const float* value = (const float*)d_in[2];
  const int*   mask  = (const int*)d_in[3];
  const float* Wq = (const float*)d_in[4];
  const float* bq = (const float*)d_in[5];
  const float* Wk = (const float*)d_in[6];
  const float* bk = (const float*)d_in[7];
  const float* Wv = (const float*)d_in[8];
  const float* bv = (const float*)d_in[9];
  const float* Wo = (const float*)d_in[10];
  const float* bo = (const float*)d_in[11];

  const int NE = B_ * S_ * D_;   // 4194304
  const int NW = D_ * D_;        // 1048576

  char* ws = (char*)d_ws;
  unsigned short* xin  = (unsigned short*)(ws);              // 3*NE bf16, dead after proj
  uint32_t*       mbits = (uint32_t*)(ws + 8388608);         // 1MB, inside dead xin
  unsigned short* wbuf = (unsigned short*)(ws + 25165824);   // 4*NW bf16
  unsigned short* qkv  = (unsigned short*)(ws + 33554432);   // 3*NE bf16 (v stored ^T)
  float2* mlbuf        = (float2*)(ws + 58720256);           // 524288
  unsigned short* aout = (unsigned short*)(ws + 59244544);   // NE bf16

  cast3<<<dim3(NE / 2048, 3), dim3(256), 0, stream>>>(query, key, value, xin, NE);
  cast4<<<dim3(NW / 2048, 4), dim3(256), 0, stream>>>(Wq, Wk, Wv, Wo, wbuf, NW);

  // q,k,v projections (z = 0,1,2); z==2 writes V transposed per head
  gemm_bt<0><<<dim3(32, 8, 3), dim3(256), 0, stream>>>(
      xin, wbuf, bq, bk, bv, qkv, 4096, 1024, 1024);

  // xin dead now: build mask bits there
  pack_mask<<<dim3(B_ * S_ * S_ / 256), dim3(256), 0, stream>>>(mask, mbits);

  float* w_out = (float*)d_out + NE;   // attn_weights region
  attn_pass1<<<dim3(32, 32), dim3(512), 0, stream>>>(qkv, qkv + NE, mbits, mlbuf);
  attn_pass2<<<dim3(32, 32), dim3(512), 0, stream>>>(
      qkv, qkv + NE, qkv + 2 * NE, mbits, mlbuf, w_out, aout);

  // output projection -> fp32 d_out
  gemm_bt<1><<<dim3(32, 8, 1), dim3(256), 0, stream>>>(
      aout, wbuf + 3 * NW, bo, bo, bo, d_out, 4096, 1024, 1024);
}

// Round 13
// 295.487 us; speedup vs baseline: 1.1130x; 1.0342x over previous
//
#include <hip/hip_runtime.h>
#include <stdint.h>

#define B_ 2
#define S_ 2048
#define D_ 1024
#define H_ 16
#define HD_ 64
#define NT_ (S_ / 64)
// SCALE * log2(e): softmax computed in exp2 domain
#define SC2_ 0.18033688011112042f

typedef __bf16 bf16_t;
typedef bf16_t bf16x8 __attribute__((ext_vector_type(8)));
typedef float f32x4 __attribute__((ext_vector_type(4)));
typedef unsigned short u16x8 __attribute__((ext_vector_type(8)));
typedef unsigned short u16x4 __attribute__((ext_vector_type(4)));

static __device__ __forceinline__ unsigned short f2b(float f) {
  return __builtin_bit_cast(unsigned short, (bf16_t)f);   // native cvt (RNE)
}

static __device__ __forceinline__ bf16x8 asb(u16x8 u) {
  return __builtin_bit_cast(bf16x8, u);
}

// ---------------- cast fp32 -> bf16, fused launches ----------------
__global__ void cast3(const float* __restrict__ a, const float* __restrict__ b,
                      const float* __restrict__ c,
                      unsigned short* __restrict__ dst, int n) {
  const float* src = blockIdx.y == 0 ? a : (blockIdx.y == 1 ? b : c);
  unsigned short* d = dst + (size_t)blockIdx.y * n;
  int i = (blockIdx.x * blockDim.x + threadIdx.x) * 8;
  if (i >= n) return;
  float4 f0 = *(const float4*)(src + i);
  float4 f1 = *(const float4*)(src + i + 4);
  u16x8 o;
  o[0] = f2b(f0.x); o[1] = f2b(f0.y); o[2] = f2b(f0.z); o[3] = f2b(f0.w);
  o[4] = f2b(f1.x); o[5] = f2b(f1.y); o[6] = f2b(f1.z); o[7] = f2b(f1.w);
  *(u16x8*)(d + i) = o;
}

__global__ void cast4(const float* __restrict__ a, const float* __restrict__ b,
                      const float* __restrict__ c, const float* __restrict__ e,
                      unsigned short* __restrict__ dst, int n) {
  const float* src = blockIdx.y == 0 ? a
                   : (blockIdx.y == 1 ? b : (blockIdx.y == 2 ? c : e));
  unsigned short* d = dst + (size_t)blockIdx.y * n;
  int i = (blockIdx.x * blockDim.x + threadIdx.x) * 8;
  if (i >= n) return;
  float4 f0 = *(const float4*)(src + i);
  float4 f1 = *(const float4*)(src + i + 4);
  u16x8 o;
  o[0] = f2b(f0.x); o[1] = f2b(f0.y); o[2] = f2b(f0.z); o[3] = f2b(f0.w);
  o[4] = f2b(f1.x); o[5] = f2b(f1.y); o[6] = f2b(f1.z); o[7] = f2b(f1.w);
  *(u16x8*)(d + i) = o;
}

// ---------------- pack mask to bits via ballot ----------------
__global__ void pack_mask(const int* __restrict__ mask,
                          uint32_t* __restrict__ mbits) {
  int i = blockIdx.x * blockDim.x + threadIdx.x;
  unsigned long long bits = __ballot(mask[i] != 0);
  if ((threadIdx.x & 63) == 0)
    *(unsigned long long*)&mbits[i >> 5] = bits;
}

// ---------------- bf16 GEMM (r2 structure): C = A[M,K] @ W[N,K]^T + bias ----
// Reg-staged + one-K-step prefetch + padded-40 LDS (proven best: r10 vs r12).
// OUTMODE 0: z=0,1 -> bf16 head-split [B,H,S,HD]; z=2 -> bf16 V^T [B,H,HD,S].
// OUTMODE 1: fp32 row-major [M,N] (non-temporal: never re-read).
template<int OUTMODE>
__global__ __launch_bounds__(256)
void gemm_bt(const unsigned short* __restrict__ Ab,
             const unsigned short* __restrict__ Wb,
             const float* __restrict__ bq_,
             const float* __restrict__ bk_,
             const float* __restrict__ bv_,
             void* __restrict__ outv,
             int M, int N, int K) {
  const int z = blockIdx.z;
  const unsigned short* A = Ab + (size_t)z * M * K;
  const unsigned short* W = Wb + (size_t)z * N * K;
  const float* bias = z == 0 ? bq_ : (z == 1 ? bk_ : bv_);

  // padded stride 40 u16 = 80B (5 mod 8 -> 2-way bank spread on b128 reads)
  __shared__ __align__(16) unsigned short As[128 * 40];
  __shared__ __align__(16) unsigned short Bs[128 * 40];

  const int tid = threadIdx.x;
  const int lane = tid & 63;
  const int wave = tid >> 6;
  const int wm = wave >> 1, wn = wave & 1;
  const int row0 = blockIdx.x * 128;
  const int col0 = blockIdx.y * 128;

  const int srow = tid >> 2;        // 0..63
  const int scol = (tid & 3) * 8;   // 0,8,16,24
  const int lr = lane & 15;
  const int lg = lane >> 4;
  const int lk = lg * 8;

  f32x4 acc[4][4] = {};

  u16x8 a0 = *(const u16x8*)&A[(size_t)(row0 + srow) * K + scol];
  u16x8 a1 = *(const u16x8*)&A[(size_t)(row0 + srow + 64) * K + scol];
  u16x8 b0 = *(const u16x8*)&W[(size_t)(col0 + srow) * K + scol];
  u16x8 b1 = *(const u16x8*)&W[(size_t)(col0 + srow + 64) * K + scol];

  for (int k0 = 0; k0 < K; k0 += 32) {
    __syncthreads();   // prior iteration's LDS reads complete
    *(u16x8*)&As[srow * 40 + scol] = a0;
    *(u16x8*)&As[(srow + 64) * 40 + scol] = a1;
    *(u16x8*)&Bs[srow * 40 + scol] = b0;
    *(u16x8*)&Bs[(srow + 64) * 40 + scol] = b1;
    if (k0 + 32 < K) {
      a0 = *(const u16x8*)&A[(size_t)(row0 + srow) * K + k0 + 32 + scol];
      a1 = *(const u16x8*)&A[(size_t)(row0 + srow + 64) * K + k0 + 32 + scol];
      b0 = *(const u16x8*)&W[(size_t)(col0 + srow) * K + k0 + 32 + scol];
      b1 = *(const u16x8*)&W[(size_t)(col0 + srow + 64) * K + k0 + 32 + scol];
    }
    __syncthreads();

    bf16x8 af[4], bfr[4];
#pragma unroll
    for (int i = 0; i < 4; ++i)
      af[i] = asb(*(const u16x8*)&As[(wm * 64 + i * 16 + lr) * 40 + lk]);
#pragma unroll
    for (int j = 0; j < 4; ++j)
      bfr[j] = asb(*(const u16x8*)&Bs[(wn * 64 + j * 16 + lr) * 40 + lk]);
#pragma unroll
    for (int i = 0; i < 4; ++i)
#pragma unroll
      for (int j = 0; j < 4; ++j)
        acc[i][j] = __builtin_amdgcn_mfma_f32_16x16x32_bf16(af[i], bfr[j], acc[i][j], 0, 0, 0);
  }

  const size_t zo = (size_t)z * M * N;
#pragma unroll
  for (int i = 0; i < 4; ++i) {
#pragma unroll
    for (int j = 0; j < 4; ++j) {
      const int row_ = row0 + wm * 64 + i * 16 + lg * 4;
      const int col = col0 + wn * 64 + j * 16 + lr;
      const float bcol = bias[col];
      if (OUTMODE == 1) {
        float* O = (float*)outv;
#pragma unroll
        for (int r = 0; r < 4; ++r)
          __builtin_nontemporal_store(acc[i][j][r] + bcol,
                                      &O[(size_t)(row_ + r) * N + col]);
      } else if (z == 2) {
        // V^T: [bh][hd][s], 4 consecutive s per lane -> 8B store
        unsigned short* O = (unsigned short*)outv + zo;
        int b = row_ >> 11, s = row_ & 2047;
        int h = col >> 6, hd = col & 63;
        u16x4 pk;
#pragma unroll
        for (int r = 0; r < 4; ++r) pk[r] = f2b(acc[i][j][r] + bcol);
        *(u16x4*)&O[(((size_t)b * H_ + h) * HD_ + hd) * S_ + s] = pk;
      } else {
        unsigned short* O = (unsigned short*)outv + zo;
        int h = col >> 6, hd = col & 63;
#pragma unroll
        for (int r = 0; r < 4; ++r) {
          int row = row_ + r;
          int b = row >> 11, s = row & 2047;
          O[(((size_t)b * H_ + h) * S_ + s) * HD_ + hd] = f2b(acc[i][j][r] + bcol);
        }
      }
    }
  }
}

// XCD-aware remap for grid (32,32): each XCD owns 4 consecutive bh values so
// its private L2 keeps those heads' K/V/Q resident across all q-tiles.
static __device__ __forceinline__ void xcd_map(int& bh, int& qt) {
  int lin = blockIdx.y * 32 + blockIdx.x;
  int xcd = lin & 7, k = lin >> 3;          // 128 blocks per XCD
  bh = (xcd << 2) | (k >> 5);               // 4 heads per XCD
  qt = k & 31;
}

// ---------------- fused attention: (m,l) loop + weights/PV loop -------------
// 64 q-rows per block, 8 waves = 4 q-subtiles x 2 sk-halves.
// Loop 1: per-row (m2,l) via swapped QK^T (exact pass1 math).
// Merge: 1KB LDS exchange, both sk-half waves compute identical merged (m,l).
// Loop 2: recompute QK^T, write normalized fp32 weights (nt), PV accumulate.
__global__ __launch_bounds__(512)
void attn_fused(const unsigned short* __restrict__ q_bh,
                const unsigned short* __restrict__ k_bh,
                const unsigned short* __restrict__ vt_g,
                const uint32_t* __restrict__ mbits,
                float* __restrict__ w_out,
                unsigned short* __restrict__ attn_out) {
  int bh, qt;
  xcd_map(bh, qt);
  const int b = bh >> 4, h = bh & (H_ - 1);
  const int q0 = qt * 64;

  __shared__ __align__(16) unsigned char smem[36864];
  unsigned short* Ks = (unsigned short*)smem;        // [64*72]  9216B
  unsigned short* Vs = Ks + 64 * 72;                 // [64*72]  9216B
  unsigned short* Ps = Vs + 64 * 72;                 // [8][16*72] 18432B
  float* cs = (float*)smem;                          // end-overlay, 17408B
  float2* mls = (float2*)Ps;                         // merge overlay, 1KB

  const int tid = threadIdx.x, lane = tid & 63, w = tid >> 6;
  const int wq = w >> 1, wk = w & 1;
  const int srow = tid >> 3, scol = (tid & 7) * 8;   // srow 0..63
  const int lr = lane & 15, lg = lane >> 4, lk = lg * 8;
  const int sq = q0 + wq * 16 + lr;
  unsigned short* Psw = Ps + w * (16 * 72);

  const unsigned short* qb = q_bh + ((size_t)bh * S_ + sq) * HD_;
  bf16x8 qf0 = asb(*(const u16x8*)&qb[lk]);
  bf16x8 qf1 = asb(*(const u16x8*)&qb[32 + lk]);

  const uint32_t* mrow = mbits + ((size_t)b * S_ + sq) * (S_ / 32);
  const unsigned short* kb = k_bh + (size_t)bh * S_ * HD_;
  const unsigned short* vb = vt_g + (size_t)bh * HD_ * S_;

  // ---------------- loop 1: per-row (m2, l) over this wave's sk-half -------
  float m2 = -__builtin_inff(), l = 0.f;
  {
    u16x8 t0 = *(const u16x8*)&kb[srow * 64 + scol];
    for (int kt = 0; kt < NT_; ++kt) {
      __syncthreads();
      *(u16x8*)&Ks[srow * 72 + scol] = t0;
      if (kt + 1 < NT_) {
        const unsigned short* kn = kb + (kt + 1) * 64 * 64;
        t0 = *(const u16x8*)&kn[srow * 64 + scol];
      }
      __syncthreads();

      uint32_t mw = mrow[kt * 2 + wk];
      const bool full = __all(mw == 0xffffffffu);

      f32x4 sa[2] = {};
#pragma unroll
      for (int jj = 0; jj < 2; ++jj) {
        const int j = wk * 2 + jj;
        bf16x8 kf0 = asb(*(const u16x8*)&Ks[(j * 16 + lr) * 72 + lk]);
        bf16x8 kf1 = asb(*(const u16x8*)&Ks[(j * 16 + lr) * 72 + 32 + lk]);
        sa[jj] = __builtin_amdgcn_mfma_f32_16x16x32_bf16(kf0, qf0, sa[jj], 0, 0, 0);
        sa[jj] = __builtin_amdgcn_mfma_f32_16x16x32_bf16(kf1, qf1, sa[jj], 0, 0, 0);
      }

      float sv[2][4];
      if (full) {
#pragma unroll
        for (int jj = 0; jj < 2; ++jj)
#pragma unroll
          for (int r = 0; r < 4; ++r) sv[jj][r] = sa[jj][r] * SC2_;
      } else {
#pragma unroll
        for (int jj = 0; jj < 2; ++jj)
#pragma unroll
          for (int r = 0; r < 4; ++r) {
            int bit = jj * 16 + lg * 4 + r;
            sv[jj][r] = ((mw >> bit) & 1) ? sa[jj][r] * SC2_ : -3.0e9f;
          }
      }
      float tm = sv[0][0];
#pragma unroll
      for (int jj = 0; jj < 2; ++jj)
#pragma unroll
        for (int r = 0; r < 4; ++r) tm = fmaxf(tm, sv[jj][r]);
      tm = fmaxf(tm, __shfl_xor(tm, 16));
      tm = fmaxf(tm, __shfl_xor(tm, 32));
      float mnew = fmaxf(m2, tm);
      float ss = 0.f;
#pragma unroll
      for (int jj = 0; jj < 2; ++jj)
#pragma unroll
        for (int r = 0; r < 4; ++r)
          ss += __builtin_amdgcn_exp2f(sv[jj][r] - mnew);
      ss += __shfl_xor(ss, 16);
      ss += __shfl_xor(ss, 32);
      l = l * __builtin_amdgcn_exp2f(m2 - mnew) + ss;
      m2 = mnew;
    }
  }

  // ---------------- merge sk-halves: all lanes get full-row (m, l) ---------
  __syncthreads();                        // Ks reads done; Ps idle -> overlay
  if (lg == 0) mls[wk * 64 + wq * 16 + lr] = make_float2(m2, l);
  __syncthreads();
  float2 h0 = mls[wq * 16 + lr];
  float2 h1 = mls[64 + wq * 16 + lr];
  const float mn = fmaxf(h0.x, h1.x);
  const float lsum = h0.y * __builtin_amdgcn_exp2f(h0.x - mn) +
                     h1.y * __builtin_amdgcn_exp2f(h1.x - mn);
  // p = exp2(sa*SC2 + off), off = -m - log2(l)  (normalization folded in)
  const float off = -mn - __builtin_amdgcn_logf(lsum);
  float* wrow = w_out + ((size_t)bh * S_ + sq) * S_;

  // ---------------- loop 2: weights write + PV ------------------------------
  u16x8 t0 = *(const u16x8*)&kb[srow * 64 + scol];
  u16x8 v0 = *(const u16x8*)&vb[(size_t)srow * S_ + scol];

  f32x4 oacc[4] = {};

  for (int kt = 0; kt < NT_; ++kt) {
    const int k0 = kt * 64;
    __syncthreads();   // prior iteration's QK/PV LDS reads (or mls reads) done
    *(u16x8*)&Ks[srow * 72 + scol] = t0;
    *(u16x8*)&Vs[srow * 72 + scol] = v0;
    if (kt + 1 < NT_) {
      t0 = *(const u16x8*)&kb[(k0 + 64 + srow) * 64 + scol];
      v0 = *(const u16x8*)&vb[(size_t)srow * S_ + k0 + 64 + scol];
    }
    __syncthreads();

    uint32_t mw = mrow[kt * 2 + wk];
    const bool full = __all(mw == 0xffffffffu);

    f32x4 sa[2] = {};
#pragma unroll
    for (int jj = 0; jj < 2; ++jj) {
      const int j = wk * 2 + jj;
      bf16x8 kf0 = asb(*(const u16x8*)&Ks[(j * 16 + lr) * 72 + lk]);
      bf16x8 kf1 = asb(*(const u16x8*)&Ks[(j * 16 + lr) * 72 + 32 + lk]);
      sa[jj] = __builtin_amdgcn_mfma_f32_16x16x32_bf16(kf0, qf0, sa[jj], 0, 0, 0);
      sa[jj] = __builtin_amdgcn_mfma_f32_16x16x32_bf16(kf1, qf1, sa[jj], 0, 0, 0);
    }

    // weights: lane owns row sq; sk = k0 + wk*32 + jj*16 + lg*4 + r
#pragma unroll
    for (int jj = 0; jj < 2; ++jj) {
      f32x4 pv;
      u16x4 pb;
      if (full) {
#pragma unroll
        for (int r = 0; r < 4; ++r) {
          float p = __builtin_amdgcn_exp2f(fmaf(sa[jj][r], SC2_, off));
          pv[r] = p;
          pb[r] = f2b(p);
        }
      } else {
#pragma unroll
        for (int r = 0; r < 4; ++r) {
          int bit = jj * 16 + lg * 4 + r;
          float x = ((mw >> bit) & 1) ? fmaf(sa[jj][r], SC2_, off) : -3.0e9f;
          float p = __builtin_amdgcn_exp2f(x);
          pv[r] = p;
          pb[r] = f2b(p);
        }
      }
      // streaming store: bypass L2 so K/V stay resident
      __builtin_nontemporal_store(pv,
          (f32x4*)&wrow[k0 + wk * 32 + jj * 16 + lg * 4]);
      *(u16x4*)&Psw[lr * 72 + wk * 32 + jj * 16 + lg * 4] = pb;
    }

    // PV over this wave's 32-sk slice: A = P (row=sq), B = V^T (col=hd)
    bf16x8 pa = asb(*(const u16x8*)&Psw[lr * 72 + wk * 32 + lk]);
#pragma unroll
    for (int j2 = 0; j2 < 4; ++j2) {
      bf16x8 vf = asb(*(const u16x8*)&Vs[(j2 * 16 + lr) * 72 + wk * 32 + lk]);
      oacc[j2] = __builtin_amdgcn_mfma_f32_16x16x32_bf16(pa, vf, oacc[j2], 0, 0, 0);
    }
  }

  // combine sk-half partials: wave (wq,1) -> LDS, wave (wq,0) adds + stores
  __syncthreads();                      // all tile LDS reads done; overlay safe
  const int ci = (wq * 64 + lane) * 17; // 17-dword stride: conflict-free
  if (wk == 1) {
#pragma unroll
    for (int j2 = 0; j2 < 4; ++j2)
#pragma unroll
      for (int r = 0; r < 4; ++r) cs[ci + j2 * 4 + r] = oacc[j2][r];
  }
  __syncthreads();
  if (wk == 0) {
    // D: col = hd = j2*16+lr, row = sq-local = lg*4+r
#pragma unroll
    for (int j2 = 0; j2 < 4; ++j2)
#pragma unroll
      for (int r = 0; r < 4; ++r) {
        float v = oacc[j2][r] + cs[ci + j2 * 4 + r];
        attn_out[((size_t)b * S_ + q0 + wq * 16 + lg * 4 + r) * D_ + h * HD_ + j2 * 16 + lr] =
            f2b(v);
      }
  }
}

// ---------------- launch ----------------
extern "C" void kernel_launch(void* const* d_in, const int* in_sizes, int n_in,
                              void* d_out, int out_size, void* d_ws, size_t ws_size,
                              hipStream_t stream) {
  const float* query = (const float*)d_in[0];
  const float* key   = (const float*)d_in[1];
  const float* value = (const float*)d_in[2];
  const int*   mask  = (const int*)d_in[3];
  const float* Wq = (const float*)d_in[4];
  const float* bq = (const float*)d_in[5];
  const float* Wk = (const float*)d_in[6];
  const float* bk = (const float*)d_in[7];
  const float* Wv = (const float*)d_in[8];
  const float* bv = (const float*)d_in[9];
  const float* Wo = (const float*)d_in[10];
  const float* bo = (const float*)d_in[11];

  const int NE = B_ * S_ * D_;   // 4194304
  const int NW = D_ * D_;        // 1048576

  char* ws = (char*)d_ws;
  unsigned short* xin  = (unsigned short*)(ws);              // 3*NE bf16, dead after proj
  uint32_t*       mbits = (uint32_t*)(ws + 8388608);         // 1MB, inside dead xin
  unsigned short* wbuf = (unsigned short*)(ws + 25165824);   // 4*NW bf16
  unsigned short* qkv  = (unsigned short*)(ws + 33554432);   // 3*NE bf16 (v stored ^T)
  unsigned short* aout = (unsigned short*)(ws + 59244544);   // NE bf16

  cast3<<<dim3(NE / 2048, 3), dim3(256), 0, stream>>>(query, key, value, xin, NE);
  cast4<<<dim3(NW / 2048, 4), dim3(256), 0, stream>>>(Wq, Wk, Wv, Wo, wbuf, NW);

  // q,k,v projections (z = 0,1,2); z==2 writes V transposed per head
  gemm_bt<0><<<dim3(32, 8, 3), dim3(256), 0, stream>>>(
      xin, wbuf, bq, bk, bv, qkv, 4096, 1024, 1024);

  // xin dead now: build mask bits there
  pack_mask<<<dim3(B_ * S_ * S_ / 256), dim3(256), 0, stream>>>(mask, mbits);

  float* w_out = (float*)d_out + NE;   // attn_weights region
  attn_fused<<<dim3(32, 32), dim3(512), 0, stream>>>(
      qkv, qkv + NE, qkv + 2 * NE, mbits, w_out, aout);

  // output projection -> fp32 d_out
  gemm_bt<1><<<dim3(32, 8, 1), dim3(256), 0, stream>>>(
      aout, wbuf + 3 * NW, bo, bo, bo, d_out, 4096, 1024, 1024);
}